// Round 7
// baseline (496.913 us; speedup 1.0000x reference)
//
#include <hip/hip_runtime.h>

using ushort_t = unsigned short;

__device__ __forceinline__ float u2f(ushort_t u){
    union{unsigned int i; float f;} x; x.i = ((unsigned int)u) << 16; return x.f;
}
__device__ __forceinline__ ushort_t f2u(float f){   // f32 -> bf16 bits, RNE
    union{float fl; unsigned int i;} x; x.fl = f;
    unsigned int r = x.i + 0x7FFFu + ((x.i >> 16) & 1u);
    return (ushort_t)(r >> 16);
}

// ---------------- Kernel 1: h = x@cw+cb ; 4x { h += LN(h@pw+pb) } -> ws (bf16) ----
// Channel attention collapses (softmax rows sum to 1 -> einsum == identity on x),
// leaving only the projection+LN residual.
// 2 rows/thread; weights in LDS read as float4 with immediate offsets: one
// ds_read_b128 feeds 8 FMAs (4 output channels x 2 rows).
__global__ __launch_bounds__(256)
void k_embed(const float* __restrict__ X,
             const float* __restrict__ CW, const float* __restrict__ CB,
             const float* __restrict__ PW, const float* __restrict__ PB,
             const float* __restrict__ PG, const float* __restrict__ PBE,
             ushort_t* __restrict__ Hws)
{
    __shared__ __align__(16) float sW[672];
    {
        const int t = threadIdx.x;
        for (int i = t; i < 352; i += 256) sW[i] = CW[i];          // [22][16] @0
        if (t < 256) { if (t < 16){ sW[352+t] = CB[t]; sW[624+t] = PB[t];
                                    sW[640+t] = PG[t]; sW[656+t] = PBE[t]; } }
        for (int i = t; i < 256; i += 256) sW[368+i] = PW[i];      // [16][16] @368
    }
    __syncthreads();
    const float4* sW4 = (const float4*)sW;

    const int g = blockIdx.x * 256 + threadIdx.x;   // 0..255999 (grid exact)

    float xv[2][22];
#pragma unroll
    for (int r = 0; r < 2; ++r){
        const float* xp = X + (size_t)(g + r*256000) * 22;
#pragma unroll
        for (int j = 0; j < 22; ++j) xv[r][j] = xp[j];
    }

    float v[2][16];
    // change matmul: v = x@CW + CB, c in groups of 4 (float4 weight rows)
#pragma unroll
    for (int cg = 0; cg < 4; ++cg){
        float acc[2][4];
#pragma unroll
        for (int q = 0; q < 4; ++q){ float b0 = sW[352 + cg*4 + q]; acc[0][q] = b0; acc[1][q] = b0; }
#pragma unroll
        for (int j = 0; j < 22; ++j){
            float4 w = sW4[j*4 + cg];          // CW[j][4cg..4cg+3]
#pragma unroll
            for (int r = 0; r < 2; ++r){
                acc[r][0] += xv[r][j]*w.x; acc[r][1] += xv[r][j]*w.y;
                acc[r][2] += xv[r][j]*w.z; acc[r][3] += xv[r][j]*w.w;
            }
        }
#pragma unroll
        for (int r = 0; r < 2; ++r)
#pragma unroll
        for (int q = 0; q < 4; ++q) v[r][cg*4+q] = acc[r][q];
    }

    // 4x: v += LN(v@PW + PB)
#pragma unroll
    for (int it = 0; it < 4; ++it){
        float u[2][16];
#pragma unroll
        for (int cg = 0; cg < 4; ++cg){
            float acc[2][4];
#pragma unroll
            for (int q = 0; q < 4; ++q){ float b0 = sW[624 + cg*4 + q]; acc[0][q] = b0; acc[1][q] = b0; }
#pragma unroll
            for (int j = 0; j < 16; ++j){
                float4 w = sW4[92 + j*4 + cg];   // PW[j][4cg..4cg+3]  (368/4 = 92)
#pragma unroll
                for (int r = 0; r < 2; ++r){
                    acc[r][0] += v[r][j]*w.x; acc[r][1] += v[r][j]*w.y;
                    acc[r][2] += v[r][j]*w.z; acc[r][3] += v[r][j]*w.w;
                }
            }
#pragma unroll
            for (int r = 0; r < 2; ++r)
#pragma unroll
            for (int q = 0; q < 4; ++q) u[r][cg*4+q] = acc[r][q];
        }
#pragma unroll
        for (int r = 0; r < 2; ++r){
            float m = 0.f;
#pragma unroll
            for (int c = 0; c < 16; ++c) m += u[r][c];
            m *= (1.f/16.f);
            float var = 0.f;
#pragma unroll
            for (int c = 0; c < 16; ++c){ float d = u[r][c] - m; var += d*d; }
            var *= (1.f/16.f);
            float inv = rsqrtf(var + 1e-5f);
#pragma unroll
            for (int c = 0; c < 16; ++c) v[r][c] += (u[r][c] - m) * inv * sW[640+c] + sW[656+c];
        }
    }

#pragma unroll
    for (int r = 0; r < 2; ++r){
        const int row = g + r*256000;
        const int b = row / 1000, s = row - b*1000;
        ushort_t* hp = Hws + b*16000 + s;
#pragma unroll
        for (int c = 0; c < 16; ++c) hp[c*1000] = f2u(v[r][c]);   // coalesced per c
    }
}

// ---------------- Kernel 2 (merged): conv1+BN+LReLU -> conv2 -> 3 transformer layers
// LDS plan:
//   conv phase: C1 bf16 [2][16][952] @0 (60928 B) | W1f @60928 | BN @61344 | W2f @61360
//   tf phase (overlaid after conv): TW[3990] @0 | T @15960 | QB @24320 | KB @33440
//                                   | VB @42560 | AT @51680   (ends 60800)
__global__ __launch_bounds__(256)
void k_main(const ushort_t* __restrict__ Hws,
            const float* __restrict__ W1, const float* __restrict__ B1,
            const float* __restrict__ BNG, const float* __restrict__ BNB,
            const float* __restrict__ BNM, const float* __restrict__ BNV,
            const float* __restrict__ W2, const float* __restrict__ B2,
            const float* __restrict__ LN1G, const float* __restrict__ LN1B,
            const float* __restrict__ QW, const float* __restrict__ QBv,
            const float* __restrict__ KW, const float* __restrict__ KBv,
            const float* __restrict__ VW, const float* __restrict__ VBv,
            const float* __restrict__ OW, const float* __restrict__ OBv,
            const float* __restrict__ LN2G, const float* __restrict__ LN2B,
            const float* __restrict__ F1W, const float* __restrict__ F1B,
            const float* __restrict__ F2W, const float* __restrict__ F2B,
            float* __restrict__ OUT)
{
    __shared__ __align__(16) char sMem[67760];
    const int tid = threadIdx.x;
    const int b   = blockIdx.x;

    // ---- conv-phase pointers ----
    ushort_t* C1  = (ushort_t*)sMem;                // [2][16][952] bf16
    float*    W1f = (float*)(sMem + 60928);         // [102]
    float*    BNf = (float*)(sMem + 61344);         // sc0 sc1 sh0 sh1
    float*    W2f = (float*)(sMem + 61360);         // [1600]

    for (int i = tid; i < 102;  i += 256) W1f[i] = W1[i];
    for (int i = tid; i < 1600; i += 256) W2f[i] = W2[i];
    if (tid < 2){
        float s0 = BNG[tid] * rsqrtf(BNV[tid] + 1e-5f);
        BNf[tid]     = s0;
        BNf[2 + tid] = BNB[tid] + (B1[tid] - BNM[tid]) * s0;
    }
    __syncthreads();

    // ---- phase 1: conv1 + BN + LeakyReLU -> C1 (5 outputs per group) ----
    // 6080 groups = 2 ch x 16 rows x 190 window-groups; each = 5 consecutive outputs.
#pragma unroll 1
    for (int k = 0; k < 24; ++k){
        int gp = tid + 256*k;
        if (gp < 6080){
            const int ik = gp / 190;          // i*16 + kh
            const int u_ = gp - ik*190;       // window group 0..189
            const int i  = ik >> 4;
            const int kh = ik & 15;
            const int w0 = u_ * 5;
            const ushort_t* hp = Hws + b*16000 + kh*1000 + w0;
            const float* w1p = W1f + i*51;
            const float sc = BNf[i], sh = BNf[2+i];
            float win[55];
#pragma unroll
            for (int t = 0; t < 55; ++t) win[t] = u2f(hp[t]);
            float acc[5];
#pragma unroll
            for (int q = 0; q < 5; ++q) acc[q] = 0.f;
#pragma unroll
            for (int t = 0; t < 51; ++t){
                float wk = w1p[t];
#pragma unroll
                for (int q = 0; q < 5; ++q) acc[q] += win[t+q] * wk;
            }
#pragma unroll
            for (int q = 0; q < 5; ++q){
                float s = acc[q]*sc + sh;
                s = s > 0.f ? s : 0.2f*s;
                C1[ik*952 + w0 + q] = f2u(s);
            }
        }
    }
    __syncthreads();

    // ---- phase 2: conv2 (16x5 window over C1, 190 threads, acc in regs) ----
    float acc10[10];
    if (tid < 190){
        const ushort_t* c1p = C1 + tid*5;
#pragma unroll
        for (int o = 0; o < 10; ++o) acc10[o] = B2[o];
#pragma unroll
        for (int kh = 0; kh < 16; ++kh){
#pragma unroll
            for (int kw = 0; kw < 5; ++kw){
                float v0 = u2f(c1p[ kh*952       + kw]);
                float v1 = u2f(c1p[(16+kh)*952   + kw]);
#pragma unroll
                for (int o = 0; o < 10; ++o)
                    acc10[o] += v0 * W2f[((o*2    )*16 + kh)*5 + kw]
                              + v1 * W2f[((o*2 + 1)*16 + kh)*5 + kw];
            }
        }
    }
    __syncthreads();   // conv reads done -> overlay

    // ---- tf-phase pointers (overlay) ----
    float* TW = (float*)sMem;              // 3990
    float* T  = (float*)(sMem + 15960);    // [190][11]
    float* QB = (float*)(sMem + 24320);    // [190][12]
    float* KB = (float*)(sMem + 33440);
    float* VB = (float*)(sMem + 42560);
    float* AT = (float*)(sMem + 51680);

    // stage transformer weights: (3,n) arrays -> per-layer blocks of stride 1330
    {
        auto cl3 = [&](int off, const float* src, int n){
            for (int i = tid; i < 3*n; i += 256){
                int L = i / n, j = i - L*n;
                TW[L*1330 + off + j] = src[i];
            }
        };
        cl3(   0, LN1G,  10);  cl3(  10, LN1B,  10);
        cl3(  20, QW,   100);  cl3( 120, QBv,   10);
        cl3( 130, KW,   100);  cl3( 230, KBv,   10);
        cl3( 240, VW,   100);  cl3( 340, VBv,   10);
        cl3( 350, OW,   100);  cl3( 450, OBv,   10);
        cl3( 460, LN2G,  10);  cl3( 470, LN2B,  10);
        cl3( 480, F1W,  400);  cl3( 880, F1B,   40);
        cl3( 920, F2W,  400);  cl3(1320, F2B,   10);
    }
    if (tid < 190){
#pragma unroll
        for (int o = 0; o < 10; ++o) T[tid*11 + o] = acc10[o];
    }
    __syncthreads();

    // ---- 3 transformer encoder layers (n=190, e=10, 5 heads, d=2) ----
    const float SCALE = 0.31622776601683794f;   // 1/sqrt(10)
    const bool act = (tid < 190);
#pragma unroll 1
    for (int L = 0; L < 3; ++L){
        const float* W = TW + L*1330;

        // phase 1: LN1 + Q/K/V projections
        if (act){
            float tv[10], y[10];
#pragma unroll
            for (int c = 0; c < 10; ++c) tv[c] = T[tid*11 + c];
            float m = 0.f;
#pragma unroll
            for (int c = 0; c < 10; ++c) m += tv[c];
            m *= 0.1f;
            float var = 0.f;
#pragma unroll
            for (int c = 0; c < 10; ++c){ float d = tv[c]-m; var += d*d; }
            var *= 0.1f;
            float inv = rsqrtf(var + 1e-5f);
#pragma unroll
            for (int c = 0; c < 10; ++c) y[c] = (tv[c]-m)*inv*W[0+c] + W[10+c];
#pragma unroll
            for (int c = 0; c < 10; ++c){
                float aq = W[120+c], ak = W[230+c], av = W[340+c];
#pragma unroll
                for (int j = 0; j < 10; ++j){
                    aq += y[j] * W[ 20 + j*10 + c];
                    ak += y[j] * W[130 + j*10 + c];
                    av += y[j] * W[240 + j*10 + c];
                }
                QB[tid*12 + c] = aq;
                KB[tid*12 + c] = ak;
                VB[tid*12 + c] = av;
            }
        }
        __syncthreads();

        // phase 2: attention, head-major (240 threads: head = tid/48, 4 queries each)
        // no-max softmax: logits are O(1); max-shift is mathematically identity.
        if (tid < 240){
            const int h5 = tid / 48;
            const int qg = tid - h5*48;
            const int q0 = qg * 4;
            float qx[4], qy[4];
#pragma unroll
            for (int i = 0; i < 4; ++i){
                int qi = q0 + i;
                if (qi < 190){
                    qx[i] = QB[qi*12 + 2*h5]     * SCALE;
                    qy[i] = QB[qi*12 + 2*h5 + 1] * SCALE;
                } else { qx[i] = 0.f; qy[i] = 0.f; }
            }
            float l[4] = {0,0,0,0}, a0[4] = {0,0,0,0}, a1[4] = {0,0,0,0};
            const float* kp = KB + 2*h5;
            const float* vp = VB + 2*h5;
#pragma unroll 2
            for (int kk = 0; kk < 190; ++kk){
                float2 kv = *(const float2*)(kp + kk*12);
                float2 vv = *(const float2*)(vp + kk*12);
#pragma unroll
                for (int i = 0; i < 4; ++i){
                    float p = __expf(qx[i]*kv.x + qy[i]*kv.y);
                    l[i] += p; a0[i] += p*vv.x; a1[i] += p*vv.y;
                }
            }
#pragma unroll
            for (int i = 0; i < 4; ++i){
                int qi = q0 + i;
                if (qi < 190){
                    float rl = 1.f / l[i];
                    AT[qi*12 + 2*h5]     = a0[i] * rl;
                    AT[qi*12 + 2*h5 + 1] = a1[i] * rl;
                }
            }
        }
        __syncthreads();

        // phase 3: out-proj + residual + LN2 + FF(GELU, running acc) + residual
        if (act){
            float tv[10], at[10];
#pragma unroll
            for (int c = 0; c < 10; ++c){ tv[c] = T[tid*11 + c]; at[c] = AT[tid*12 + c]; }
#pragma unroll
            for (int c = 0; c < 10; ++c){
                float a = W[450+c];
#pragma unroll
                for (int j = 0; j < 10; ++j) a += at[j] * W[350 + j*10 + c];
                tv[c] += a;
            }
            float m = 0.f;
#pragma unroll
            for (int c = 0; c < 10; ++c) m += tv[c];
            m *= 0.1f;
            float var = 0.f;
#pragma unroll
            for (int c = 0; c < 10; ++c){ float d = tv[c]-m; var += d*d; }
            var *= 0.1f;
            float inv = rsqrtf(var + 1e-5f);
            float y2[10];
#pragma unroll
            for (int c = 0; c < 10; ++c) y2[c] = (tv[c]-m)*inv*W[460+c] + W[470+c];
            float d10[10];
#pragma unroll
            for (int c = 0; c < 10; ++c) d10[c] = W[1320+c];
#pragma unroll
            for (int j = 0; j < 40; ++j){
                float a = W[880+j];
#pragma unroll
                for (int c = 0; c < 10; ++c) a += y2[c] * W[480 + c*40 + j];
                float gj = 0.5f * a * (1.f + erff(a * 0.70710678118654752f));  // exact GELU
#pragma unroll
                for (int c = 0; c < 10; ++c) d10[c] += gj * W[920 + j*10 + c];
            }
#pragma unroll
            for (int c = 0; c < 10; ++c) T[tid*11 + c] = tv[c] + d10[c];
        }
        __syncthreads();
    }

    if (act){
#pragma unroll
        for (int c = 0; c < 10; ++c)
            OUT[(size_t)b*1900 + tid*10 + c] = T[tid*11 + c];
    }
}

extern "C" void kernel_launch(void* const* d_in, const int* in_sizes, int n_in,
                              void* d_out, int out_size, void* d_ws, size_t ws_size,
                              hipStream_t stream)
{
    (void)ws_size; (void)n_in; (void)out_size;
    const int B = in_sizes[0] / 22000;   // 512
    auto in = [&](int i){ return (const float*)d_in[i]; };
    ushort_t* Hws = (ushort_t*)d_ws;     // B*16000 bf16 = 16.38 MB

    k_embed<<<1000, 256, 0, stream>>>(
        in(0), in(1), in(2), in(11), in(12), in(13), in(14), Hws);

    k_main<<<B, 256, 0, stream>>>(
        Hws,
        in(15), in(16), in(17), in(18), in(19), in(20), in(21), in(22),
        in(23), in(24), in(25), in(26), in(27), in(28), in(29), in(30),
        in(31), in(32), in(33), in(34), in(35), in(36), in(37), in(38),
        (float*)d_out);
}

// Round 8
// 398.865 us; speedup vs baseline: 1.2458x; 1.2458x over previous
//
#include <hip/hip_runtime.h>

typedef unsigned short ushort_t;

__device__ __forceinline__ float u2f(ushort_t u){
    union{unsigned int i; float f;} x; x.i = ((unsigned int)u) << 16; return x.f;
}
__device__ __forceinline__ ushort_t f2u(float f){   // f32 -> bf16 bits, RNE
    union{float fl; unsigned int i;} x; x.fl = f;
    unsigned int r = x.i + 0x7FFFu + ((x.i >> 16) & 1u);
    return (ushort_t)(r >> 16);
}

#define REP10(M) M(0)M(1)M(2)M(3)M(4)M(5)M(6)M(7)M(8)M(9)
#define REP16(M) M(0)M(1)M(2)M(3)M(4)M(5)M(6)M(7)M(8)M(9)M(10)M(11)M(12)M(13)M(14)M(15)
#define REP22(M) REP16(M) M(16)M(17)M(18)M(19)M(20)M(21)
#define REP55(M) M(0)M(1)M(2)M(3)M(4)M(5)M(6)M(7)M(8)M(9)M(10)M(11)M(12)M(13)M(14)M(15)M(16)M(17)M(18)M(19)M(20)M(21)M(22)M(23)M(24)M(25)M(26)M(27)M(28)M(29)M(30)M(31)M(32)M(33)M(34)M(35)M(36)M(37)M(38)M(39)M(40)M(41)M(42)M(43)M(44)M(45)M(46)M(47)M(48)M(49)M(50)M(51)M(52)M(53)M(54)

// ================= Kernel 1: h = x@cw+cb ; 4x { h += LN16(h@pw+pb) } -> ws bf16 ===
// Channel attention collapses (softmax rows sum to 1 -> einsum == identity on x).
// ALL state in named scalars (no private arrays -> nothing can go to scratch).
__global__ __launch_bounds__(256)
void k_embed(const float* __restrict__ X,
             const float* __restrict__ CW, const float* __restrict__ CB,
             const float* __restrict__ PW, const float* __restrict__ PB,
             const float* __restrict__ PG, const float* __restrict__ PBE,
             ushort_t* __restrict__ Hws)
{
    const int idx = blockIdx.x * 256 + threadIdx.x;   // grid exact: 512000
    const int b = idx / 1000, s = idx - b * 1000;
    const float* xp = X + (size_t)idx * 22;

#define E_DX(j) float x##j = xp[j];
    REP22(E_DX)
#define E_DV(c) float v##c = CB[c];
    REP16(E_DV)
#define E_CH(j) { const float xx = x##j; const float* w = CW + (j)*16; \
    v0+=xx*w[0]; v1+=xx*w[1]; v2+=xx*w[2]; v3+=xx*w[3]; \
    v4+=xx*w[4]; v5+=xx*w[5]; v6+=xx*w[6]; v7+=xx*w[7]; \
    v8+=xx*w[8]; v9+=xx*w[9]; v10+=xx*w[10]; v11+=xx*w[11]; \
    v12+=xx*w[12]; v13+=xx*w[13]; v14+=xx*w[14]; v15+=xx*w[15]; }
    REP22(E_CH)

#define E_DU(c) float u##c = PB[c];
#define E_PJ(j) { const float vv = v##j; const float* w = PW + (j)*16; \
    u0+=vv*w[0]; u1+=vv*w[1]; u2+=vv*w[2]; u3+=vv*w[3]; \
    u4+=vv*w[4]; u5+=vv*w[5]; u6+=vv*w[6]; u7+=vv*w[7]; \
    u8+=vv*w[8]; u9+=vv*w[9]; u10+=vv*w[10]; u11+=vv*w[11]; \
    u12+=vv*w[12]; u13+=vv*w[13]; u14+=vv*w[14]; u15+=vv*w[15]; }
#define E_DS(c) const float d##c = u##c - m;
#define E_UP(c) v##c += d##c * inv * PG[c] + PBE[c];
#define E_LNIT { \
    REP16(E_DU) REP16(E_PJ) \
    float m = (((u0+u1)+(u2+u3))+((u4+u5)+(u6+u7)))+(((u8+u9)+(u10+u11))+((u12+u13)+(u14+u15))); \
    m *= 0.0625f; \
    REP16(E_DS) \
    float var = (((d0*d0+d1*d1)+(d2*d2+d3*d3))+((d4*d4+d5*d5)+(d6*d6+d7*d7)))+(((d8*d8+d9*d9)+(d10*d10+d11*d11))+((d12*d12+d13*d13)+(d14*d14+d15*d15))); \
    var *= 0.0625f; \
    float inv = rsqrtf(var + 1e-5f); \
    REP16(E_UP) }

    E_LNIT E_LNIT E_LNIT E_LNIT

    ushort_t* hp = Hws + b*16000 + s;
#define E_ST(c) hp[(c)*1000] = f2u(v##c);
    REP16(E_ST)
}

// ================= Kernel 2: conv1+BN+LReLU fused into conv2 -> t (ws f32) ========
// conv1 outputs have ZERO reuse across conv2 output columns (stride 5, kw<5), so
// fuse: per (b,w) recompute the 2x16x5 conv1 values from the h window in LDS.
// Rolling-tap formulation: each input element is loaded ONCE into a named scalar
// and feeds up to 10 FMAs with compile-time-folded guards. No arrays anywhere.
__global__ __launch_bounds__(256)
void k_conv(const ushort_t* __restrict__ Hws,
            const float* __restrict__ W1, const float* __restrict__ B1,
            const float* __restrict__ BNG, const float* __restrict__ BNB,
            const float* __restrict__ BNM, const float* __restrict__ BNV,
            const float* __restrict__ W2, const float* __restrict__ B2,
            float* __restrict__ Tws)
{
    __shared__ ushort_t sH[16000];   // h[16][1000] bf16 = 32 KB -> 4 blocks/CU
    const int tid = threadIdx.x, b = blockIdx.x;

    { // coalesced stage (byte offset b*32000 is 4-aligned)
        const unsigned int* src = (const unsigned int*)(Hws + b*16000);
        unsigned int* dst = (unsigned int*)sH;
        for (int i = tid; i < 8000; i += 256) dst[i] = src[i];
    }
    const float sc0 = BNG[0]*rsqrtf(BNV[0]+1e-5f);
    const float sc1 = BNG[1]*rsqrtf(BNV[1]+1e-5f);
    const float sh0 = BNB[0] + (B1[0]-BNM[0])*sc0;
    const float sh1 = BNB[1] + (B1[1]-BNM[1])*sc1;
    __syncthreads();

    if (tid < 190){
        const int w5 = tid*5;
#define C_DT(o) float t##o = B2[o];
        REP10(C_DT)
        const float* w1a = W1;        // conv1 ch 0 taps [51]
        const float* w1b = W1 + 51;   // conv1 ch 1 taps
        for (int kh = 0; kh < 16; ++kh){
            const ushort_t* hp = sH + kh*1000 + w5;
            float a0=0.f,a1=0.f,a2=0.f,a3=0.f,a4=0.f;
            float b0_=0.f,b1_=0.f,b2_=0.f,b3_=0.f,b4_=0.f;
#define C_TAP(e) { const float cur = u2f(hp[e]); \
            if ((e) < 51)              { a0+=cur*w1a[(e)];   b0_+=cur*w1b[(e)];   } \
            if ((e) >= 1 && (e) < 52)  { a1+=cur*w1a[(e)-1]; b1_+=cur*w1b[(e)-1]; } \
            if ((e) >= 2 && (e) < 53)  { a2+=cur*w1a[(e)-2]; b2_+=cur*w1b[(e)-2]; } \
            if ((e) >= 3 && (e) < 54)  { a3+=cur*w1a[(e)-3]; b3_+=cur*w1b[(e)-3]; } \
            if ((e) >= 4)              { a4+=cur*w1a[(e)-4]; b4_+=cur*w1b[(e)-4]; } }
            REP55(C_TAP)
            // BN + LeakyReLU(0.2)
#define C_LR(q) { a##q = a##q*sc0 + sh0; a##q = a##q > 0.f ? a##q : 0.2f*a##q; \
                  b##q##_ = b##q##_*sc1 + sh1; b##q##_ = b##q##_ > 0.f ? b##q##_ : 0.2f*b##q##_; }
            C_LR(0) C_LR(1) C_LR(2) C_LR(3) C_LR(4)
            // conv2 accumulate: W2 [10][2][16][5]
#define C_C2(o) { const float* wa = W2 + (((o)*2  )*16 + kh)*5; \
                  const float* wb = W2 + (((o)*2+1)*16 + kh)*5; \
        t##o += a0*wa[0]+a1*wa[1]+a2*wa[2]+a3*wa[3]+a4*wa[4] \
              + b0_*wb[0]+b1_*wb[1]+b2_*wb[2]+b3_*wb[3]+b4_*wb[4]; }
            REP10(C_C2)
        }
        float* op = Tws + (size_t)b*1900 + tid*10;
#define C_ST(o) op[o] = t##o;
        REP10(C_ST)
    }
}

// ================= Kernel 3: 3 transformer layers (n=190, e=10, 5 heads, d=2) =====
// LDS holds only shared row-state; all per-thread state is named scalars.
__global__ __launch_bounds__(256)
void k_tf(const float* __restrict__ Tws,
          const float* __restrict__ LN1G, const float* __restrict__ LN1B,
          const float* __restrict__ QW, const float* __restrict__ QBv,
          const float* __restrict__ KW, const float* __restrict__ KBv,
          const float* __restrict__ VW, const float* __restrict__ VBv,
          const float* __restrict__ OW, const float* __restrict__ OBv,
          const float* __restrict__ LN2G, const float* __restrict__ LN2B,
          const float* __restrict__ F1W, const float* __restrict__ F1B,
          const float* __restrict__ F2W, const float* __restrict__ F2B,
          float* __restrict__ OUT)
{
    __shared__ __align__(16) float T [190*11];
    __shared__ __align__(16) float QB[190*12];
    __shared__ __align__(16) float KB[190*12];
    __shared__ __align__(16) float VB[190*12];
    __shared__ __align__(16) float AT[190*12];

    const int tid = threadIdx.x, b = blockIdx.x;
    for (int i = tid; i < 1900; i += 256){
        int r = i/10, c = i - r*10;
        T[r*11 + c] = Tws[(size_t)b*1900 + i];
    }
    __syncthreads();

    const float SCALE = 0.31622776601683794f;   // 1/sqrt(10)
    const bool act = (tid < 190);
#pragma unroll 1
    for (int L = 0; L < 3; ++L){
        const float* ln1g = LN1G + L*10; const float* ln1b = LN1B + L*10;
        const float* qw = QW + L*100;    const float* qb = QBv + L*10;
        const float* kw = KW + L*100;    const float* kb = KBv + L*10;
        const float* vw = VW + L*100;    const float* vb = VBv + L*10;
        const float* ow = OW + L*100;    const float* ob = OBv + L*10;
        const float* ln2g = LN2G + L*10; const float* ln2b = LN2B + L*10;
        const float* f1w = F1W + L*400;  const float* f1b = F1B + L*40;
        const float* f2w = F2W + L*400;  const float* f2b = F2B + L*10;

        // ---- phase 1: LN1 + Q/K/V projections ----
        if (act){
#define T_TV(c) float tv##c = T[tid*11 + c];
            REP10(T_TV)
            float m = (((tv0+tv1)+(tv2+tv3))+((tv4+tv5)+(tv6+tv7)))+(tv8+tv9);
            m *= 0.1f;
#define T_D1(c) const float e1##c = tv##c - m;
            REP10(T_D1)
            float var = (((e10*e10+e11*e11)+(e12*e12+e13*e13))+((e14*e14+e15*e15)+(e16*e16+e17*e17)))+(e18*e18+e19*e19);
            var *= 0.1f;
            float inv = rsqrtf(var + 1e-5f);
#define T_Y(c) const float y##c = e1##c*inv*ln1g[c] + ln1b[c];
            REP10(T_Y)
#define T_PQ(c) { float aq = qb[c] + y0*qw[c] + y1*qw[10+c] + y2*qw[20+c] + y3*qw[30+c] + y4*qw[40+c] \
                           + y5*qw[50+c] + y6*qw[60+c] + y7*qw[70+c] + y8*qw[80+c] + y9*qw[90+c]; \
                  QB[tid*12 + c] = aq; }
            REP10(T_PQ)
#define T_PK(c) { float ak = kb[c] + y0*kw[c] + y1*kw[10+c] + y2*kw[20+c] + y3*kw[30+c] + y4*kw[40+c] \
                           + y5*kw[50+c] + y6*kw[60+c] + y7*kw[70+c] + y8*kw[80+c] + y9*kw[90+c]; \
                  KB[tid*12 + c] = ak; }
            REP10(T_PK)
#define T_PV(c) { float av = vb[c] + y0*vw[c] + y1*vw[10+c] + y2*vw[20+c] + y3*vw[30+c] + y4*vw[40+c] \
                           + y5*vw[50+c] + y6*vw[60+c] + y7*vw[70+c] + y8*vw[80+c] + y9*vw[90+c]; \
                  VB[tid*12 + c] = av; }
            REP10(T_PV)
        }
        __syncthreads();

        // ---- phase 2: attention, head-major (240 threads; 4 queries/thread) ----
        // no-max softmax: logits O(1); jax's max-shift is mathematically identity.
        if (tid < 240){
            const int h5 = tid / 48;
            const int qg = tid - h5*48;
            const int q0 = qg * 4;
#define T_LQ(i) float qx##i, qy##i; { const int qi = q0 + i; \
            if (qi < 190){ qx##i = QB[qi*12 + 2*h5]*SCALE; qy##i = QB[qi*12 + 2*h5 + 1]*SCALE; } \
            else { qx##i = 0.f; qy##i = 0.f; } }
            T_LQ(0) T_LQ(1) T_LQ(2) T_LQ(3)
            float l0=0.f,l1=0.f,l2=0.f,l3=0.f;
            float p00=0.f,p01=0.f,p10=0.f,p11=0.f,p20=0.f,p21=0.f,p30=0.f,p31=0.f;
            const float* kp = KB + 2*h5;
            const float* vp = VB + 2*h5;
            for (int kk = 0; kk < 190; ++kk){
                const float2 kv = *(const float2*)(kp + kk*12);
                const float2 vv = *(const float2*)(vp + kk*12);
                const float e0 = __expf(qx0*kv.x + qy0*kv.y);
                const float e1 = __expf(qx1*kv.x + qy1*kv.y);
                const float e2 = __expf(qx2*kv.x + qy2*kv.y);
                const float e3 = __expf(qx3*kv.x + qy3*kv.y);
                l0 += e0; p00 += e0*vv.x; p01 += e0*vv.y;
                l1 += e1; p10 += e1*vv.x; p11 += e1*vv.y;
                l2 += e2; p20 += e2*vv.x; p21 += e2*vv.y;
                l3 += e3; p30 += e3*vv.x; p31 += e3*vv.y;
            }
#define T_SA(i) { const int qi = q0 + i; if (qi < 190){ const float rl = 1.f/l##i; \
                  AT[qi*12 + 2*h5] = p##i##0*rl; AT[qi*12 + 2*h5 + 1] = p##i##1*rl; } }
            T_SA(0) T_SA(1) T_SA(2) T_SA(3)
        }
        __syncthreads();

        // ---- phase 3: out-proj + residual + LN2 + FF(GELU exact) + residual ----
        if (act){
#define T_TV2(c) float w##c = T[tid*11 + c];
            REP10(T_TV2)
#define T_AT(c) const float at##c = AT[tid*12 + c];
            REP10(T_AT)
#define T_OP(c) w##c += ob[c] + at0*ow[c] + at1*ow[10+c] + at2*ow[20+c] + at3*ow[30+c] + at4*ow[40+c] \
                       + at5*ow[50+c] + at6*ow[60+c] + at7*ow[70+c] + at8*ow[80+c] + at9*ow[90+c];
            REP10(T_OP)
            float m2 = (((w0+w1)+(w2+w3))+((w4+w5)+(w6+w7)))+(w8+w9);
            m2 *= 0.1f;
#define T_D2(c) const float e2##c = w##c - m2;
            REP10(T_D2)
            float var2 = (((e20*e20+e21*e21)+(e22*e22+e23*e23))+((e24*e24+e25*e25)+(e26*e26+e27*e27)))+(e28*e28+e29*e29);
            var2 *= 0.1f;
            float inv2 = rsqrtf(var2 + 1e-5f);
#define T_Z(c) const float z##c = e2##c*inv2*ln2g[c] + ln2b[c];
            REP10(T_Z)
#define T_DD(c) float dd##c = f2b[c];
            REP10(T_DD)
#pragma unroll 4
            for (int j = 0; j < 40; ++j){
                float aj = f1b[j] + z0*f1w[j] + z1*f1w[40+j] + z2*f1w[80+j] + z3*f1w[120+j] + z4*f1w[160+j]
                         + z5*f1w[200+j] + z6*f1w[240+j] + z7*f1w[280+j] + z8*f1w[320+j] + z9*f1w[360+j];
                const float gj = 0.5f * aj * (1.f + erff(aj * 0.70710678118654752f));
                const float* w2p = f2w + j*10;
                dd0 += gj*w2p[0]; dd1 += gj*w2p[1]; dd2 += gj*w2p[2]; dd3 += gj*w2p[3]; dd4 += gj*w2p[4];
                dd5 += gj*w2p[5]; dd6 += gj*w2p[6]; dd7 += gj*w2p[7]; dd8 += gj*w2p[8]; dd9 += gj*w2p[9];
            }
#define T_WB(c) T[tid*11 + c] = w##c + dd##c;
            REP10(T_WB)
        }
        __syncthreads();
    }

    if (act){
        float* op = OUT + (size_t)b*1900 + tid*10;
#define T_OUT(c) op[c] = T[tid*11 + c];
        REP10(T_OUT)
    }
}

extern "C" void kernel_launch(void* const* d_in, const int* in_sizes, int n_in,
                              void* d_out, int out_size, void* d_ws, size_t ws_size,
                              hipStream_t stream)
{
    (void)ws_size; (void)n_in; (void)out_size;
    const int B = in_sizes[0] / 22000;   // 512
    auto in = [&](int i){ return (const float*)d_in[i]; };
    ushort_t* Hws = (ushort_t*)d_ws;                              // B*16000 bf16 = 16.38 MB
    float*    Tws = (float*)((char*)d_ws + (size_t)B*16000*2);    // B*1900 f32

    k_embed<<<(B*1000 + 255)/256, 256, 0, stream>>>(
        in(0), in(1), in(2), in(11), in(12), in(13), in(14), Hws);

    k_conv<<<B, 256, 0, stream>>>(
        Hws, in(15), in(16), in(17), in(18), in(19), in(20), in(21), in(22), Tws);

    k_tf<<<B, 256, 0, stream>>>(
        Tws,
        in(23), in(24), in(25), in(26), in(27), in(28), in(29), in(30),
        in(31), in(32), in(33), in(34), in(35), in(36), in(37), in(38),
        (float*)d_out);
}